// Round 1
// baseline (121.598 us; speedup 1.0000x reference)
//
#include <hip/hip_runtime.h>
#include <stdint.h>

#define K_   128
#define GD_  128
#define PSTR 20   // floats per (b,k) param record
#define KPW  32   // k's per wave (K_ / 4 waves)
#define PPB  128  // points per block (2 per thread)

static __device__ __forceinline__ float fast_exp2(float x) {
#if __has_builtin(__builtin_amdgcn_exp2f)
    return __builtin_amdgcn_exp2f(x);
#else
    return exp2f(x);
#endif
}

// broadcast lane `l`'s value of v to all lanes; result is wave-uniform (SGPR)
static __device__ __forceinline__ float bcast_lane(float v, int l) {
#if __has_builtin(__builtin_amdgcn_readlane)
    return __uint_as_float((unsigned)__builtin_amdgcn_readlane((int)__float_as_uint(v), l));
#else
    return __shfl(v, l, 64);
#endif
}

// ---------------- param kernel: one thread per (b,k) ----------------
//   G  = A_next * (R_next * R^T)            (3x3, grid-space transform)
//   v  = A_next * (c_next - R_rel*c) + t_next
//   q  = 2*s*log2e * c,  r = log2(c^2) - s*log2e*|c|^2,  s2n = -s*log2e
// Per point:  log2(w) = q.p + s2n*|p|^2 + r,  gridcoord = (Σw(G p + v))/Σw
__global__ void surf_param_kernel(
    const float* __restrict__ constants,
    const float* __restrict__ scales,
    const float* __restrict__ rotations,
    const float* __restrict__ centers,
    const float* __restrict__ w2g,
    float* __restrict__ params,
    float* __restrict__ out,
    int B)
{
    int idx = blockIdx.x * blockDim.x + threadIdx.x;
    if (idx == 0) out[0] = 0.0f;           // fused memset (runs before main kernel)
    if (idx >= B * K_) return;
    int b = idx / K_, k = idx - b * K_;
    int bn = (b + 1 == B) ? 0 : (b + 1);
    const float L2E = 1.4426950408889634f;

    const float* R  = rotations + (size_t)(b  * K_ + k) * 9;
    const float* Rt = rotations + (size_t)(bn * K_ + k) * 9;
    float m[9];
#pragma unroll
    for (int i = 0; i < 3; ++i)
#pragma unroll
        for (int l = 0; l < 3; ++l)
            m[i * 3 + l] = Rt[i * 3 + 0] * R[l * 3 + 0]
                         + Rt[i * 3 + 1] * R[l * 3 + 1]
                         + Rt[i * 3 + 2] * R[l * 3 + 2];

    const float* Aw = w2g + (size_t)bn * 16;   // rows [a0 a1 a2 t]
    float G[9], A[9] = {Aw[0], Aw[1], Aw[2], Aw[4], Aw[5], Aw[6], Aw[8], Aw[9], Aw[10]};
    float T[3] = {Aw[3], Aw[7], Aw[11]};
#pragma unroll
    for (int i = 0; i < 3; ++i)
#pragma unroll
        for (int l = 0; l < 3; ++l)
            G[i * 3 + l] = A[i * 3 + 0] * m[0 * 3 + l]
                         + A[i * 3 + 1] * m[1 * 3 + l]
                         + A[i * 3 + 2] * m[2 * 3 + l];

    const float* c  = centers + (size_t)(b  * K_ + k) * 3;
    const float* ct = centers + (size_t)(bn * K_ + k) * 3;
    float c0 = c[0], c1 = c[1], c2 = c[2];
    float vw0 = ct[0] - (m[0] * c0 + m[1] * c1 + m[2] * c2);
    float vw1 = ct[1] - (m[3] * c0 + m[4] * c1 + m[5] * c2);
    float vw2 = ct[2] - (m[6] * c0 + m[7] * c1 + m[8] * c2);
    float v0 = A[0] * vw0 + A[1] * vw1 + A[2] * vw2 + T[0];
    float v1 = A[3] * vw0 + A[4] * vw1 + A[5] * vw2 + T[1];
    float v2 = A[6] * vw0 + A[7] * vw1 + A[8] * vw2 + T[2];

    float sig = scales[b * K_ + k];
    float s   = 1.0f / (2.0f * sig * sig);
    float con = constants[b * K_ + k];
    float s2n = -s * L2E;
    float r   = log2f(con * con) + s2n * (c0 * c0 + c1 * c1 + c2 * c2);

    float* o = params + (size_t)idx * PSTR;
    o[0] = G[0]; o[1] = G[1]; o[2] = G[2]; o[3] = G[3];
    o[4] = G[4]; o[5] = G[5]; o[6] = G[6]; o[7] = G[7];
    o[8] = G[8]; o[9] = v0;  o[10] = v1;  o[11] = v2;
    o[12] = -2.0f * s2n * c0;
    o[13] = -2.0f * s2n * c1;
    o[14] = -2.0f * s2n * c2;
    o[15] = r;
    o[16] = s2n;
    o[17] = 0.f; o[18] = 0.f; o[19] = 0.f;
}

// ---------------- main kernel ----------------
// Block = 256 threads = 4 waves, 128 points (2/thread). Wave w covers k in
// [32w,32w+32) for all 128 points; partials combined through LDS.
// K-loop is memory-free: each wave's 640 param floats live lane-distributed
// in 10 VGPRs (lane l holds floats [10l,10l+10)); per-k params are
// broadcast to SGPRs via v_readlane (lanes 2kk / 2kk+1). Grid = 1564 blocks
// = 6.11 blocks/CU: balanced (max/avg 1.15 vs 1.31 at 784 blocks) and
// ~6 waves/SIMD for residual latency (point loads, grid gather).
__global__ __launch_bounds__(256, 6) void surf_loss_kernel(
    const float* __restrict__ sp,      // (B,N,6)
    const float* __restrict__ grid,    // (B,GD,GD,GD)
    const float* __restrict__ params,  // (B,K,PSTR) precomputed
    float* __restrict__ out,
    int N, int B, int bpb)
{
    __shared__ float  lds_par[K_ * PSTR];      // 10 KB (staging for reg cache)
    __shared__ float4 lds_part[4 * 2 * 64];    // 8 KB: [wave][j][lane]
    __shared__ float  red[4];

    const int tid  = threadIdx.x;
    const int lane = tid & 63;
    const int wave = tid >> 6;
    const int blk  = blockIdx.x;
    const int b    = blk / bpb;
    const int base = (blk - b * bpb) * PPB;
    const int bn   = (b + 1 == B) ? 0 : (b + 1);

    // stage batch's param table into LDS, coalesced float4
    {
        const float4* Pv = (const float4*)(params + (size_t)b * K_ * PSTR);
        float4* Lv = (float4*)lds_par;
        for (int t = tid; t < K_ * PSTR / 4; t += 256)
            Lv[t] = Pv[t];
    }

    // load this thread's 2 points (same points in every wave, same lane)
    float px[2], py[2], pz[2], pq[2];
    float ax[2], ay[2], az[2], aw[2];
    const float* spb = sp + (size_t)b * N * 6;
#pragma unroll
    for (int j = 0; j < 2; ++j) {
        int n = base + j * 64 + lane;
        int nn = (n < N) ? n : 0;
        const float* q = spb + (size_t)nn * 6;
        px[j] = q[0]; py[j] = q[1]; pz[j] = q[2];
        pq[j] = px[j] * px[j] + py[j] * py[j] + pz[j] * pz[j];
        ax[j] = 0.f; ay[j] = 0.f; az[j] = 0.f; aw[j] = 0.f;
    }

    __syncthreads();

    // per-lane register cache of this wave's 32 param records (640 floats):
    // lane l holds slice floats [10l, 10l+10)  →  record kk = lanes 2kk,2kk+1
    const int k0 = wave * KPW;
    float c0, c1, c2, c3, c4, c5, c6, c7, c8, c9;
    {
        const float2* f2p = (const float2*)(lds_par + k0 * PSTR) + (size_t)lane * 5;
        float2 d0 = f2p[0], d1 = f2p[1], d2 = f2p[2], d3 = f2p[3], d4 = f2p[4];
        c0 = d0.x; c1 = d0.y; c2 = d1.x; c3 = d1.y; c4 = d2.x;
        c5 = d2.y; c6 = d3.x; c7 = d3.y; c8 = d4.x; c9 = d4.y;
    }

    // K loop: pure VALU, params broadcast to SGPRs per k
#pragma unroll 2
    for (int kk = 0; kk < KPW; ++kk) {
        const int l0 = kk + kk, l1 = l0 + 1;
        // record layout: [G0..G8, v0] in lane l0, [v1 v2 q0 q1 q2 r s2 ...] in lane l1
        const float g0 = bcast_lane(c0, l0), g1 = bcast_lane(c1, l0), g2 = bcast_lane(c2, l0);
        const float g3 = bcast_lane(c3, l0), g4 = bcast_lane(c4, l0), g5 = bcast_lane(c5, l0);
        const float g6 = bcast_lane(c6, l0), g7 = bcast_lane(c7, l0), g8 = bcast_lane(c8, l0);
        const float v0 = bcast_lane(c9, l0);
        const float v1 = bcast_lane(c0, l1), v2 = bcast_lane(c1, l1);
        const float q0 = bcast_lane(c2, l1), q1 = bcast_lane(c3, l1), q2 = bcast_lane(c4, l1);
        const float rr = bcast_lane(c5, l1), s2 = bcast_lane(c6, l1);
#pragma unroll
        for (int j = 0; j < 2; ++j) {
            float e = rr + q0 * px[j] + q1 * py[j] + q2 * pz[j] + s2 * pq[j];
            float w = fast_exp2(e);
            float tx = v0 + g0 * px[j] + g1 * py[j] + g2 * pz[j];
            float ty = v1 + g3 * px[j] + g4 * py[j] + g5 * pz[j];
            float tz = v2 + g6 * px[j] + g7 * py[j] + g8 * pz[j];
            ax[j] += w * tx;
            ay[j] += w * ty;
            az[j] += w * tz;
            aw[j] += w;
        }
    }

    // write partials: [wave][j][lane]
#pragma unroll
    for (int j = 0; j < 2; ++j)
        lds_part[((wave * 2 + j) << 6) + lane] = make_float4(ax[j], ay[j], az[j], aw[j]);
    __syncthreads();

    // epilogue: wave 0 takes point group 0, wave 1 group 1
    float accum = 0.0f;
    if (wave < 2) {
        int n = base + wave * 64 + lane;
        if (n < N) {
            float sx = 0.f, sy = 0.f, sz = 0.f, sw = 0.f;
#pragma unroll
            for (int w = 0; w < 4; ++w) {
                float4 t = lds_part[((w * 2 + wave) << 6) + lane];
                sx += t.x; sy += t.y; sz += t.z; sw += t.w;
            }
            float inv = 1.0f / sw;
            float x = fminf(fmaxf(sx * inv, 0.0f), (float)(GD_ - 1));
            float y = fminf(fmaxf(sy * inv, 0.0f), (float)(GD_ - 1));
            float z = fminf(fmaxf(sz * inv, 0.0f), (float)(GD_ - 1));
            float x0f = floorf(x), y0f = floorf(y), z0f = floorf(z);
            float fx = x - x0f, fy = y - y0f, fz = z - z0f;
            int x0 = (int)x0f, y0 = (int)y0f, z0 = (int)z0f;
            int x1 = x0 + 1 > GD_ - 1 ? GD_ - 1 : x0 + 1;
            int y1 = y0 + 1 > GD_ - 1 ? GD_ - 1 : y0 + 1;
            int z1 = z0 + 1 > GD_ - 1 ? GD_ - 1 : z0 + 1;
            const float* gb = grid + (size_t)bn * GD_ * GD_ * GD_;
            int zy00 = (z0 * GD_ + y0) * GD_;
            int zy01 = (z0 * GD_ + y1) * GD_;
            int zy10 = (z1 * GD_ + y0) * GD_;
            int zy11 = (z1 * GD_ + y1) * GD_;
            float c000 = gb[zy00 + x0], c001 = gb[zy00 + x1];
            float c010 = gb[zy01 + x0], c011 = gb[zy01 + x1];
            float c100 = gb[zy10 + x0], c101 = gb[zy10 + x1];
            float c110 = gb[zy11 + x0], c111 = gb[zy11 + x1];
            float ofx = 1.0f - fx, ofy = 1.0f - fy, ofz = 1.0f - fz;
            float c00 = c000 * ofx + c001 * fx;
            float c01 = c010 * ofx + c011 * fx;
            float c10 = c100 * ofx + c101 * fx;
            float c11 = c110 * ofx + c111 * fx;
            float cc0 = c00 * ofy + c01 * fy;
            float cc1 = c10 * ofy + c11 * fy;
            float sdf = cc0 * ofz + cc1 * fz;
            accum = sdf * sdf;
        }
    }

    // per-wave shuffle reduce, then one atomic per block
#pragma unroll
    for (int off = 32; off > 0; off >>= 1)
        accum += __shfl_down(accum, off, 64);
    if (lane == 0) red[wave] = accum;
    __syncthreads();
    if (tid == 0)
        atomicAdd(out, (red[0] + red[1] + red[2] + red[3]) * (1.0f / (float)N));
}

extern "C" void kernel_launch(void* const* d_in, const int* in_sizes, int n_in,
                              void* d_out, int out_size, void* d_ws, size_t ws_size,
                              hipStream_t stream) {
    const float* constants = (const float*)d_in[0];
    const float* scales    = (const float*)d_in[1];
    const float* rotations = (const float*)d_in[2];
    const float* centers   = (const float*)d_in[3];
    const float* sp        = (const float*)d_in[4];
    const float* grid      = (const float*)d_in[5];
    const float* w2g       = (const float*)d_in[6];
    float* out = (float*)d_out;
    float* params = (float*)d_ws;            // B*K_*PSTR floats = 40 KB

    const int B = in_sizes[6] / 16;          // 4
    const int N = in_sizes[4] / (6 * B);     // 50000

    int np = B * K_;
    hipLaunchKernelGGL(surf_param_kernel, dim3((np + 255) / 256), dim3(256), 0, stream,
                       constants, scales, rotations, centers, w2g, params, out, B);

    const int bpb = (N + PPB - 1) / PPB;     // blocks per batch (128 points/block)
    hipLaunchKernelGGL(surf_loss_kernel, dim3(B * bpb), dim3(256), 0, stream,
                       sp, grid, params, out, N, B, bpb);
}

// Round 2
// 111.405 us; speedup vs baseline: 1.0915x; 1.0915x over previous
//
#include <hip/hip_runtime.h>
#include <stdint.h>

#define K_   128
#define GD_  128
#define PSTR 20   // floats per (b,k) param record
#define KPW  32   // k's per wave (K_ / 4 waves)

static __device__ __forceinline__ float fast_exp2(float x) {
#if __has_builtin(__builtin_amdgcn_exp2f)
    return __builtin_amdgcn_exp2f(x);
#else
    return exp2f(x);
#endif
}

// ---------------- param kernel: one thread per (b,k) ----------------
//   G  = A_next * (R_next * R^T)            (3x3, grid-space transform)
//   v  = A_next * (c_next - R_rel*c) + t_next
//   q  = 2*s*log2e * c,  r = log2(c^2) - s*log2e*|c|^2,  s2n = -s*log2e
// Per point:  log2(w) = q.p + s2n*|p|^2 + r,  gridcoord = (Σw(G p + v))/Σw
// (world2grid + [-1,1] normalization + grid_sample denorm cancel exactly.)
__global__ void surf_param_kernel(
    const float* __restrict__ constants,
    const float* __restrict__ scales,
    const float* __restrict__ rotations,
    const float* __restrict__ centers,
    const float* __restrict__ w2g,
    float* __restrict__ params,
    float* __restrict__ out,
    int B)
{
    int idx = blockIdx.x * blockDim.x + threadIdx.x;
    if (idx == 0) out[0] = 0.0f;           // fused memset (runs before main kernel)
    if (idx >= B * K_) return;
    int b = idx / K_, k = idx - b * K_;
    int bn = (b + 1 == B) ? 0 : (b + 1);
    const float L2E = 1.4426950408889634f;

    const float* R  = rotations + (size_t)(b  * K_ + k) * 9;
    const float* Rt = rotations + (size_t)(bn * K_ + k) * 9;
    float m[9];
#pragma unroll
    for (int i = 0; i < 3; ++i)
#pragma unroll
        for (int l = 0; l < 3; ++l)
            m[i * 3 + l] = Rt[i * 3 + 0] * R[l * 3 + 0]
                         + Rt[i * 3 + 1] * R[l * 3 + 1]
                         + Rt[i * 3 + 2] * R[l * 3 + 2];

    const float* Aw = w2g + (size_t)bn * 16;   // rows [a0 a1 a2 t]
    float G[9], A[9] = {Aw[0], Aw[1], Aw[2], Aw[4], Aw[5], Aw[6], Aw[8], Aw[9], Aw[10]};
    float T[3] = {Aw[3], Aw[7], Aw[11]};
#pragma unroll
    for (int i = 0; i < 3; ++i)
#pragma unroll
        for (int l = 0; l < 3; ++l)
            G[i * 3 + l] = A[i * 3 + 0] * m[0 * 3 + l]
                         + A[i * 3 + 1] * m[1 * 3 + l]
                         + A[i * 3 + 2] * m[2 * 3 + l];

    const float* c  = centers + (size_t)(b  * K_ + k) * 3;
    const float* ct = centers + (size_t)(bn * K_ + k) * 3;
    float c0 = c[0], c1 = c[1], c2 = c[2];
    float vw0 = ct[0] - (m[0] * c0 + m[1] * c1 + m[2] * c2);
    float vw1 = ct[1] - (m[3] * c0 + m[4] * c1 + m[5] * c2);
    float vw2 = ct[2] - (m[6] * c0 + m[7] * c1 + m[8] * c2);
    float v0 = A[0] * vw0 + A[1] * vw1 + A[2] * vw2 + T[0];
    float v1 = A[3] * vw0 + A[4] * vw1 + A[5] * vw2 + T[1];
    float v2 = A[6] * vw0 + A[7] * vw1 + A[8] * vw2 + T[2];

    float sig = scales[b * K_ + k];
    float s   = 1.0f / (2.0f * sig * sig);
    float con = constants[b * K_ + k];
    float s2n = -s * L2E;
    float r   = log2f(con * con) + s2n * (c0 * c0 + c1 * c1 + c2 * c2);

    float* o = params + (size_t)idx * PSTR;
    o[0] = G[0]; o[1] = G[1]; o[2] = G[2]; o[3] = G[3];
    o[4] = G[4]; o[5] = G[5]; o[6] = G[6]; o[7] = G[7];
    o[8] = G[8]; o[9] = v0;  o[10] = v1;  o[11] = v2;
    o[12] = -2.0f * s2n * c0;
    o[13] = -2.0f * s2n * c1;
    o[14] = -2.0f * s2n * c2;
    o[15] = r;
    o[16] = s2n;
    o[17] = 0.f; o[18] = 0.f; o[19] = 0.f;
}

// ---------------- main kernel: K split across the block's 4 waves ----------------
// Block = 256 threads = 4 waves, handles 256 points of one batch (4/thread).
// Wave w computes partial (ax,ay,az,aw) over k in [32w, 32w+32); partials
// combined through LDS; epilogue split by wave.
// K-loop param reads go through the SCALAR pipe: k0 is made provably
// wave-uniform via readfirstlane, so the record loads select s_load_dwordx4
// from the 40 KB L2-resident table (sK$-hit). This removes the entire DS
// broadcast stream (the measured ~10 µs binding pipe) and the LDS staging +
// first barrier; params feed the FMAs as SGPR operands (0 VALU-issue cost).
__global__ __launch_bounds__(256) void surf_loss_kernel(
    const float* __restrict__ sp,      // (B,N,6)
    const float* __restrict__ grid,    // (B,GD,GD,GD)
    const float* __restrict__ params,  // (B,K,PSTR) precomputed
    float* __restrict__ out,
    int N, int B, int bpb)
{
    __shared__ float4 lds_part[4 * 4 * 64];    // 16 KB: [wave][j][lane]
    __shared__ float  red[4];

    const int tid  = threadIdx.x;
    const int lane = tid & 63;
    const int wave = tid >> 6;
    const int blk  = blockIdx.x;
    const int b    = blk / bpb;
    const int base = (blk - b * bpb) * 256;
    const int bn   = (b + 1 == B) ? 0 : (b + 1);

    // load this thread's 4 points (same 4 points in every wave, same lane)
    float px[4], py[4], pz[4], pq[4];
    float ax[4], ay[4], az[4], aw[4];
    const float* spb = sp + (size_t)b * N * 6;
#pragma unroll
    for (int j = 0; j < 4; ++j) {
        int n = base + j * 64 + lane;
        int nn = (n < N) ? n : 0;
        const float* q = spb + (size_t)nn * 6;
        px[j] = q[0]; py[j] = q[1]; pz[j] = q[2];
        pq[j] = px[j] * px[j] + py[j] * py[j] + pz[j] * pz[j];
        ax[j] = 0.f; ay[j] = 0.f; az[j] = 0.f; aw[j] = 0.f;
    }

    // wave-uniform k base, provably uniform to the compiler -> scalar loads
    const int k0 = __builtin_amdgcn_readfirstlane(wave * KPW);
    const float* __restrict__ pb = params + (size_t)b * K_ * PSTR + (size_t)k0 * PSTR;

    // K loop: this wave's 32 k's; params via scalar pipe (SGPR broadcast)
#pragma unroll 2
    for (int kk = 0; kk < KPW; ++kk) {
        const float* pk = pb + kk * PSTR;
        const float4 f0 = *(const float4*)(pk + 0);   // G00 G01 G02 G10
        const float4 f1 = *(const float4*)(pk + 4);   // G11 G12 G20 G21
        const float4 f2 = *(const float4*)(pk + 8);   // G22 v0  v1  v2
        const float4 f3 = *(const float4*)(pk + 12);  // q0  q1  q2  r
        const float  s2 = pk[16];
#pragma unroll
        for (int j = 0; j < 4; ++j) {
            float e = f3.w + f3.x * px[j] + f3.y * py[j] + f3.z * pz[j] + s2 * pq[j];
            float w = fast_exp2(e);
            float tx = f2.y + f0.x * px[j] + f0.y * py[j] + f0.z * pz[j];
            float ty = f2.z + f0.w * px[j] + f1.x * py[j] + f1.y * pz[j];
            float tz = f2.w + f1.z * px[j] + f1.w * py[j] + f2.x * pz[j];
            ax[j] += w * tx;
            ay[j] += w * ty;
            az[j] += w * tz;
            aw[j] += w;
        }
    }

    // write partials: [wave][j][lane]
#pragma unroll
    for (int j = 0; j < 4; ++j)
        lds_part[((wave * 4 + j) << 6) + lane] = make_float4(ax[j], ay[j], az[j], aw[j]);
    __syncthreads();

    // epilogue: wave w takes point group j == wave
    float accum = 0.0f;
    {
        int n = base + wave * 64 + lane;
        if (n < N) {
            float sx = 0.f, sy = 0.f, sz = 0.f, sw = 0.f;
#pragma unroll
            for (int w = 0; w < 4; ++w) {
                float4 t = lds_part[((w * 4 + wave) << 6) + lane];
                sx += t.x; sy += t.y; sz += t.z; sw += t.w;
            }
            float inv = 1.0f / sw;
            float x = fminf(fmaxf(sx * inv, 0.0f), (float)(GD_ - 1));
            float y = fminf(fmaxf(sy * inv, 0.0f), (float)(GD_ - 1));
            float z = fminf(fmaxf(sz * inv, 0.0f), (float)(GD_ - 1));
            float x0f = floorf(x), y0f = floorf(y), z0f = floorf(z);
            float fx = x - x0f, fy = y - y0f, fz = z - z0f;
            int x0 = (int)x0f, y0 = (int)y0f, z0 = (int)z0f;
            int x1 = x0 + 1 > GD_ - 1 ? GD_ - 1 : x0 + 1;
            int y1 = y0 + 1 > GD_ - 1 ? GD_ - 1 : y0 + 1;
            int z1 = z0 + 1 > GD_ - 1 ? GD_ - 1 : z0 + 1;
            const float* gb = grid + (size_t)bn * GD_ * GD_ * GD_;
            int zy00 = (z0 * GD_ + y0) * GD_;
            int zy01 = (z0 * GD_ + y1) * GD_;
            int zy10 = (z1 * GD_ + y0) * GD_;
            int zy11 = (z1 * GD_ + y1) * GD_;
            float c000 = gb[zy00 + x0], c001 = gb[zy00 + x1];
            float c010 = gb[zy01 + x0], c011 = gb[zy01 + x1];
            float c100 = gb[zy10 + x0], c101 = gb[zy10 + x1];
            float c110 = gb[zy11 + x0], c111 = gb[zy11 + x1];
            float ofx = 1.0f - fx, ofy = 1.0f - fy, ofz = 1.0f - fz;
            float c00 = c000 * ofx + c001 * fx;
            float c01 = c010 * ofx + c011 * fx;
            float c10 = c100 * ofx + c101 * fx;
            float c11 = c110 * ofx + c111 * fx;
            float c0 = c00 * ofy + c01 * fy;
            float c1 = c10 * ofy + c11 * fy;
            float sdf = c0 * ofz + c1 * fz;
            accum = sdf * sdf;
        }
    }

    // per-wave shuffle reduce, then one atomic per block
#pragma unroll
    for (int off = 32; off > 0; off >>= 1)
        accum += __shfl_down(accum, off, 64);
    if (lane == 0) red[wave] = accum;
    __syncthreads();
    if (tid == 0)
        atomicAdd(out, (red[0] + red[1] + red[2] + red[3]) * (1.0f / (float)N));
}

extern "C" void kernel_launch(void* const* d_in, const int* in_sizes, int n_in,
                              void* d_out, int out_size, void* d_ws, size_t ws_size,
                              hipStream_t stream) {
    const float* constants = (const float*)d_in[0];
    const float* scales    = (const float*)d_in[1];
    const float* rotations = (const float*)d_in[2];
    const float* centers   = (const float*)d_in[3];
    const float* sp        = (const float*)d_in[4];
    const float* grid      = (const float*)d_in[5];
    const float* w2g       = (const float*)d_in[6];
    float* out = (float*)d_out;
    float* params = (float*)d_ws;            // B*K_*PSTR floats = 40 KB

    const int B = in_sizes[6] / 16;          // 4
    const int N = in_sizes[4] / (6 * B);     // 50000

    int np = B * K_;
    hipLaunchKernelGGL(surf_param_kernel, dim3((np + 255) / 256), dim3(256), 0, stream,
                       constants, scales, rotations, centers, w2g, params, out, B);

    const int bpb = (N + 255) / 256;         // blocks per batch (256 points/block)
    hipLaunchKernelGGL(surf_loss_kernel, dim3(B * bpb), dim3(256), 0, stream,
                       sp, grid, params, out, N, B, bpb);
}

// Round 3
// 110.527 us; speedup vs baseline: 1.1002x; 1.0079x over previous
//
#include <hip/hip_runtime.h>
#include <stdint.h>

#define K_   128
#define GD_  128
#define PSTR 20   // floats per (b,k) param record
#define KPW  32   // k's per wave (K_ / 4 waves)

typedef float v2f __attribute__((ext_vector_type(2)));

static __device__ __forceinline__ float fast_exp2(float x) {
#if __has_builtin(__builtin_amdgcn_exp2f)
    return __builtin_amdgcn_exp2f(x);
#else
    return exp2f(x);
#endif
}

// ---------------- param kernel: one thread per (b,k) ----------------
//   G  = A_next * (R_next * R^T)            (3x3, grid-space transform)
//   v  = A_next * (c_next - R_rel*c) + t_next
//   q  = 2*s*log2e * c,  r = log2(c^2) - s*log2e*|c|^2,  s2n = -s*log2e
// Per point:  log2(w) = q.p + s2n*|p|^2 + r,  gridcoord = (Σw(G p + v))/Σw
// (world2grid + [-1,1] normalization + grid_sample denorm cancel exactly.)
__global__ void surf_param_kernel(
    const float* __restrict__ constants,
    const float* __restrict__ scales,
    const float* __restrict__ rotations,
    const float* __restrict__ centers,
    const float* __restrict__ w2g,
    float* __restrict__ params,
    float* __restrict__ out,
    int B)
{
    int idx = blockIdx.x * blockDim.x + threadIdx.x;
    if (idx == 0) out[0] = 0.0f;           // fused memset (runs before main kernel)
    if (idx >= B * K_) return;
    int b = idx / K_, k = idx - b * K_;
    int bn = (b + 1 == B) ? 0 : (b + 1);
    const float L2E = 1.4426950408889634f;

    const float* R  = rotations + (size_t)(b  * K_ + k) * 9;
    const float* Rt = rotations + (size_t)(bn * K_ + k) * 9;
    float m[9];
#pragma unroll
    for (int i = 0; i < 3; ++i)
#pragma unroll
        for (int l = 0; l < 3; ++l)
            m[i * 3 + l] = Rt[i * 3 + 0] * R[l * 3 + 0]
                         + Rt[i * 3 + 1] * R[l * 3 + 1]
                         + Rt[i * 3 + 2] * R[l * 3 + 2];

    const float* Aw = w2g + (size_t)bn * 16;   // rows [a0 a1 a2 t]
    float G[9], A[9] = {Aw[0], Aw[1], Aw[2], Aw[4], Aw[5], Aw[6], Aw[8], Aw[9], Aw[10]};
    float T[3] = {Aw[3], Aw[7], Aw[11]};
#pragma unroll
    for (int i = 0; i < 3; ++i)
#pragma unroll
        for (int l = 0; l < 3; ++l)
            G[i * 3 + l] = A[i * 3 + 0] * m[0 * 3 + l]
                         + A[i * 3 + 1] * m[1 * 3 + l]
                         + A[i * 3 + 2] * m[2 * 3 + l];

    const float* c  = centers + (size_t)(b  * K_ + k) * 3;
    const float* ct = centers + (size_t)(bn * K_ + k) * 3;
    float c0 = c[0], c1 = c[1], c2 = c[2];
    float vw0 = ct[0] - (m[0] * c0 + m[1] * c1 + m[2] * c2);
    float vw1 = ct[1] - (m[3] * c0 + m[4] * c1 + m[5] * c2);
    float vw2 = ct[2] - (m[6] * c0 + m[7] * c1 + m[8] * c2);
    float v0 = A[0] * vw0 + A[1] * vw1 + A[2] * vw2 + T[0];
    float v1 = A[3] * vw0 + A[4] * vw1 + A[5] * vw2 + T[1];
    float v2 = A[6] * vw0 + A[7] * vw1 + A[8] * vw2 + T[2];

    float sig = scales[b * K_ + k];
    float s   = 1.0f / (2.0f * sig * sig);
    float con = constants[b * K_ + k];
    float s2n = -s * L2E;
    float r   = log2f(con * con) + s2n * (c0 * c0 + c1 * c1 + c2 * c2);

    float* o = params + (size_t)idx * PSTR;
    o[0] = G[0]; o[1] = G[1]; o[2] = G[2]; o[3] = G[3];
    o[4] = G[4]; o[5] = G[5]; o[6] = G[6]; o[7] = G[7];
    o[8] = G[8]; o[9] = v0;  o[10] = v1;  o[11] = v2;
    o[12] = -2.0f * s2n * c0;
    o[13] = -2.0f * s2n * c1;
    o[14] = -2.0f * s2n * c2;
    o[15] = r;
    o[16] = s2n;
    o[17] = 0.f; o[18] = 0.f; o[19] = 0.f;
}

// ---------------- main kernel: K split across the block's 4 waves ----------------
// Block = 256 threads = 4 waves, handles 256 points of one batch (4/thread,
// held as 2 point-PAIRS in <2 x float> vectors). Wave w covers k in
// [32w,32w+32); partials combined through LDS; epilogue split by wave.
// Params arrive via the scalar pipe (k0 readfirstlane-uniform -> s_load,
// SGPR operands). Inner loop is packed FP32: every FMA is a v_pk_fma_f32
// (2 points/instr), cutting VALU issue from ~19 to ~10.5 slots/point·k —
// the measured binding pipe (R1: +38% slots -> +9.7 µs; R2: removing DS
// was neutral -> VALU-issue-bound).
__global__ __launch_bounds__(256) void surf_loss_kernel(
    const float* __restrict__ sp,      // (B,N,6)
    const float* __restrict__ grid,    // (B,GD,GD,GD)
    const float* __restrict__ params,  // (B,K,PSTR) precomputed
    float* __restrict__ out,
    int N, int B, int bpb)
{
    __shared__ float4 lds_part[4 * 4 * 64];    // 16 KB: [wave][j][lane]
    __shared__ float  red[4];

    const int tid  = threadIdx.x;
    const int lane = tid & 63;
    const int wave = tid >> 6;
    const int blk  = blockIdx.x;
    const int b    = blk / bpb;
    const int base = (blk - b * bpb) * 256;
    const int bn   = (b + 1 == B) ? 0 : (b + 1);

    // load this thread's 4 points as 2 pairs (same points in every wave/lane)
    v2f px2[2], py2[2], pz2[2], pq2[2];
    v2f ax2[2], ay2[2], az2[2], aw2[2];
    const float* spb = sp + (size_t)b * N * 6;
#pragma unroll
    for (int j = 0; j < 4; ++j) {
        int n = base + j * 64 + lane;
        int nn = (n < N) ? n : 0;
        const float* q = spb + (size_t)nn * 6;
        float x = q[0], y = q[1], z = q[2];
        px2[j >> 1][j & 1] = x;
        py2[j >> 1][j & 1] = y;
        pz2[j >> 1][j & 1] = z;
        pq2[j >> 1][j & 1] = x * x + y * y + z * z;
    }
#pragma unroll
    for (int g = 0; g < 2; ++g) {
        ax2[g] = (v2f)0.f; ay2[g] = (v2f)0.f; az2[g] = (v2f)0.f; aw2[g] = (v2f)0.f;
    }

    // wave-uniform k base, provably uniform to the compiler -> scalar loads
    const int k0 = __builtin_amdgcn_readfirstlane(wave * KPW);
    const float* __restrict__ pb = params + (size_t)b * K_ * PSTR + (size_t)k0 * PSTR;

    // K loop: this wave's 32 k's; params via scalar pipe, math via v_pk_fma_f32
#pragma unroll 2
    for (int kk = 0; kk < KPW; ++kk) {
        const float* pk = pb + kk * PSTR;
        const float4 f0 = *(const float4*)(pk + 0);   // G00 G01 G02 G10
        const float4 f1 = *(const float4*)(pk + 4);   // G11 G12 G20 G21
        const float4 f2 = *(const float4*)(pk + 8);   // G22 v0  v1  v2
        const float4 f3 = *(const float4*)(pk + 12);  // q0  q1  q2  r
        const float  s2 = pk[16];
#pragma unroll
        for (int g = 0; g < 2; ++g) {
            v2f e  = f3.w + f3.x * px2[g] + f3.y * py2[g] + f3.z * pz2[g] + s2 * pq2[g];
            v2f w2;
            w2.x = fast_exp2(e.x);
            w2.y = fast_exp2(e.y);
            v2f tx = f2.y + f0.x * px2[g] + f0.y * py2[g] + f0.z * pz2[g];
            v2f ty = f2.z + f0.w * px2[g] + f1.x * py2[g] + f1.y * pz2[g];
            v2f tz = f2.w + f1.z * px2[g] + f1.w * py2[g] + f2.x * pz2[g];
            ax2[g] += w2 * tx;
            ay2[g] += w2 * ty;
            az2[g] += w2 * tz;
            aw2[g] += w2;
        }
    }

    // write partials: [wave][j][lane]
#pragma unroll
    for (int j = 0; j < 4; ++j)
        lds_part[((wave * 4 + j) << 6) + lane] =
            make_float4(ax2[j >> 1][j & 1], ay2[j >> 1][j & 1],
                        az2[j >> 1][j & 1], aw2[j >> 1][j & 1]);
    __syncthreads();

    // epilogue: wave w takes point group j == wave
    float accum = 0.0f;
    {
        int n = base + wave * 64 + lane;
        if (n < N) {
            float sx = 0.f, sy = 0.f, sz = 0.f, sw = 0.f;
#pragma unroll
            for (int w = 0; w < 4; ++w) {
                float4 t = lds_part[((w * 4 + wave) << 6) + lane];
                sx += t.x; sy += t.y; sz += t.z; sw += t.w;
            }
            float inv = 1.0f / sw;
            float x = fminf(fmaxf(sx * inv, 0.0f), (float)(GD_ - 1));
            float y = fminf(fmaxf(sy * inv, 0.0f), (float)(GD_ - 1));
            float z = fminf(fmaxf(sz * inv, 0.0f), (float)(GD_ - 1));
            float x0f = floorf(x), y0f = floorf(y), z0f = floorf(z);
            float fx = x - x0f, fy = y - y0f, fz = z - z0f;
            int x0 = (int)x0f, y0 = (int)y0f, z0 = (int)z0f;
            int x1 = x0 + 1 > GD_ - 1 ? GD_ - 1 : x0 + 1;
            int y1 = y0 + 1 > GD_ - 1 ? GD_ - 1 : y0 + 1;
            int z1 = z0 + 1 > GD_ - 1 ? GD_ - 1 : z0 + 1;
            const float* gb = grid + (size_t)bn * GD_ * GD_ * GD_;
            int zy00 = (z0 * GD_ + y0) * GD_;
            int zy01 = (z0 * GD_ + y1) * GD_;
            int zy10 = (z1 * GD_ + y0) * GD_;
            int zy11 = (z1 * GD_ + y1) * GD_;
            float c000 = gb[zy00 + x0], c001 = gb[zy00 + x1];
            float c010 = gb[zy01 + x0], c011 = gb[zy01 + x1];
            float c100 = gb[zy10 + x0], c101 = gb[zy10 + x1];
            float c110 = gb[zy11 + x0], c111 = gb[zy11 + x1];
            float ofx = 1.0f - fx, ofy = 1.0f - fy, ofz = 1.0f - fz;
            float c00 = c000 * ofx + c001 * fx;
            float c01 = c010 * ofx + c011 * fx;
            float c10 = c100 * ofx + c101 * fx;
            float c11 = c110 * ofx + c111 * fx;
            float c0 = c00 * ofy + c01 * fy;
            float c1 = c10 * ofy + c11 * fy;
            float sdf = c0 * ofz + c1 * fz;
            accum = sdf * sdf;
        }
    }

    // per-wave shuffle reduce, then one atomic per block
#pragma unroll
    for (int off = 32; off > 0; off >>= 1)
        accum += __shfl_down(accum, off, 64);
    if (lane == 0) red[wave] = accum;
    __syncthreads();
    if (tid == 0)
        atomicAdd(out, (red[0] + red[1] + red[2] + red[3]) * (1.0f / (float)N));
}

extern "C" void kernel_launch(void* const* d_in, const int* in_sizes, int n_in,
                              void* d_out, int out_size, void* d_ws, size_t ws_size,
                              hipStream_t stream) {
    const float* constants = (const float*)d_in[0];
    const float* scales    = (const float*)d_in[1];
    const float* rotations = (const float*)d_in[2];
    const float* centers   = (const float*)d_in[3];
    const float* sp        = (const float*)d_in[4];
    const float* grid      = (const float*)d_in[5];
    const float* w2g       = (const float*)d_in[6];
    float* out = (float*)d_out;
    float* params = (float*)d_ws;            // B*K_*PSTR floats = 40 KB

    const int B = in_sizes[6] / 16;          // 4
    const int N = in_sizes[4] / (6 * B);     // 50000

    int np = B * K_;
    hipLaunchKernelGGL(surf_param_kernel, dim3((np + 255) / 256), dim3(256), 0, stream,
                       constants, scales, rotations, centers, w2g, params, out, B);

    const int bpb = (N + 255) / 256;         // blocks per batch (256 points/block)
    hipLaunchKernelGGL(surf_loss_kernel, dim3(B * bpb), dim3(256), 0, stream,
                       sp, grid, params, out, N, B, bpb);
}